// Round 1
// baseline (228.842 us; speedup 1.0000x reference)
//
#include <hip/hip_runtime.h>

// NonLocalBlock B=8, L=2048, C=512, CI=256 (fp32 in/out).
// Round 7:
//   - score_softmax: issue-early LDS double-buffer over the FLATTENED
//     (batch, k0) loop: 32 pipeline steps, ONE barrier per step, next tile's
//     global_load_lds issued right after the barrier so loads fly during the
//     frag-load + MFMA phase (same structure as out_kernel). Was: 32 serial
//     stage -> barrier(vmcnt(0) drain) -> compute -> barrier cycles.
//   - out_kernel unchanged (already issue-early dbuf).
//   All-fp16, XOR k-chunk swizzle (0 bank conflicts).

#define NB 8
#define NL 2048
#define NC 512
#define NCI 256

using f16x8 = __attribute__((ext_vector_type(8))) _Float16;
using f32x4 = __attribute__((ext_vector_type(4))) float;
typedef unsigned short u16;

__device__ __forceinline__ u16 f16b(float x) {
    _Float16 h = (_Float16)x;
    return __builtin_bit_cast(u16, h);
}
__device__ __forceinline__ float f16tof(u16 u) {
    return (float)__builtin_bit_cast(_Float16, u);
}
__device__ __forceinline__ void gload16(const void* g, void* l) {
    __builtin_amdgcn_global_load_lds((__attribute__((address_space(1))) void*)g,
                                     (__attribute__((address_space(3))) void*)l,
                                     16, 0, 0);
}

// ---- cvt: X fp32 -> fp16 --------------------------------------------------
__global__ __launch_bounds__(256) void cvt_x_kernel(const float* __restrict__ X,
                                                    u16* __restrict__ Xf)
{
    size_t i = (size_t)blockIdx.x * 256 + threadIdx.x;   // per 8 elements
    const float4* X4 = (const float4*)X;
    float4 a = X4[2 * i], b = X4[2 * i + 1];
    u16 o[8] = {f16b(a.x), f16b(a.y), f16b(a.z), f16b(a.w),
                f16b(b.x), f16b(b.y), f16b(b.z), f16b(b.w)};
    ((uint4*)Xf)[i] = *(const uint4*)o;
}

// ---- cvt: transpose weights to [n][k] fp16 --------------------------------
__global__ __launch_bounds__(256) void cvt_w_kernel(
    const float* __restrict__ Wx, const float* __restrict__ Wy, const float* __restrict__ Wo,
    u16* __restrict__ WxT, u16* __restrict__ WyT, u16* __restrict__ WoT)
{
    const int bid = blockIdx.x, t = threadIdx.x;
#pragma unroll
    for (int kk = 0; kk < 2; ++kk) {
        const int k = t + kk * 256;
        if (bid < 256)      WxT[(size_t)bid * NC + k] = f16b(Wx[(size_t)k * NCI + bid]);
        else if (bid < 512) WyT[(size_t)(bid - 256) * NC + k] = f16b(Wy[(size_t)k * NCI + (bid - 256)]);
        else                WoT[(size_t)(bid - 512) * NC + k] = f16b(Wo[(size_t)k * NC + (bid - 512)]);
    }
}

// ---- projections: grid (128, 8); cb 0-1 xp, 2-3 yp, 4-7 op (transposed) ----
__global__ __launch_bounds__(256) void proj_kernel(
    const u16* __restrict__ Xf,
    const u16* __restrict__ WxT, const u16* __restrict__ WyT, const u16* __restrict__ WoT,
    const float* __restrict__ bx, const float* __restrict__ by, const float* __restrict__ bo,
    u16* __restrict__ xp, u16* __restrict__ yp, u16* __restrict__ opT)
{
    __shared__ __align__(16) u16 SM[17408];   // As 8192 + Bs 8192; Ts reuse 128x136
    u16* As = SM;
    u16* Bs = SM + 8192;

    const int tid = threadIdx.x;
    const int w = tid >> 6, lane = tid & 63;
    const int row0 = blockIdx.x * 128;
    const int cb = blockIdx.y;

    const u16* W; const float* bias; int n0, path;
    if (cb < 2)      { path = 0; n0 = cb * 128;       W = WxT; bias = bx; }
    else if (cb < 4) { path = 1; n0 = (cb - 2) * 128; W = WyT; bias = by; }
    else             { path = 2; n0 = (cb - 4) * 128; W = WoT; bias = bo; }

    f32x4 acc[4][4] = {};
    const int wm = (w & 1) * 64, wn = (w >> 1) * 64;
    const int fr = lane & 15, fq = lane >> 4;

    for (int k0 = 0; k0 < NC; k0 += 64) {
#pragma unroll
        for (int pass = 0; pass < 4; ++pass) {
            const int cbase = pass * 256 + w * 64;   // wave-uniform
            const int chunk = cbase + lane;
            const int r = chunk >> 3;
            const int kc = (chunk & 7) ^ (r & 7);    // XOR-swizzled k-chunk
            gload16(Xf + (size_t)(row0 + r) * NC + k0 + kc * 8, (char*)As + cbase * 16);
            gload16(W  + (size_t)(n0  + r) * NC + k0 + kc * 8, (char*)Bs + cbase * 16);
        }
        __syncthreads();
        f16x8 a[4][2], b[4][2];
#pragma unroll
        for (int mi = 0; mi < 4; ++mi)
#pragma unroll
            for (int kt = 0; kt < 2; ++kt)
                a[mi][kt] = *(const f16x8*)&As[(wm + mi * 16 + fr) * 64 + ((kt * 4 + fq) ^ (fr & 7)) * 8];
#pragma unroll
        for (int ni = 0; ni < 4; ++ni)
#pragma unroll
            for (int kt = 0; kt < 2; ++kt)
                b[ni][kt] = *(const f16x8*)&Bs[(wn + ni * 16 + fr) * 64 + ((kt * 4 + fq) ^ (fr & 7)) * 8];
#pragma unroll
        for (int kt = 0; kt < 2; ++kt)
#pragma unroll
            for (int mi = 0; mi < 4; ++mi)
#pragma unroll
                for (int ni = 0; ni < 4; ++ni)
                    acc[mi][ni] = __builtin_amdgcn_mfma_f32_16x16x32_f16(a[mi][kt], b[ni][kt], acc[mi][ni], 0, 0, 0);
        __syncthreads();
    }

    if (path != 2) {
        u16* O = (path == 0) ? xp : yp;
#pragma unroll
        for (int mi = 0; mi < 4; ++mi) {
            const int grow = row0 + wm + mi * 16 + fq * 4;
#pragma unroll
            for (int ni = 0; ni < 4; ++ni) {
                const int gcol = n0 + wn + ni * 16 + fr;
                const float bv = bias[gcol];
#pragma unroll
                for (int r = 0; r < 4; ++r)
                    O[(size_t)(grow + r) * NCI + gcol] = f16b(acc[mi][ni][r] + bv);
            }
        }
    } else {
        u16* Ts = SM;   // 128 x 136 fp16 transpose staging
#pragma unroll
        for (int mi = 0; mi < 4; ++mi) {
            const int mb = wm + mi * 16 + fq * 4;
#pragma unroll
            for (int ni = 0; ni < 4; ++ni) {
                const int nl_ = wn + ni * 16 + fr;
                const float bv = bias[n0 + nl_];
#pragma unroll
                for (int r = 0; r < 4; ++r)
                    Ts[nl_ * 136 + mb + r] = f16b(acc[mi][ni][r] + bv);
            }
        }
        __syncthreads();
        const int b = row0 >> 11, m0 = row0 & 2047;
        u16* dst = opT + (size_t)b * NC * NL + (size_t)n0 * NL + m0;
        for (int i = tid; i < 128 * 16; i += 256) {
            const int c = i >> 4, ch = i & 15;
            uint4 v = *(const uint4*)&Ts[c * 136 + ch * 8];
            *(uint4*)&dst[(size_t)c * NL + ch * 8] = v;
        }
    }
}

// ---- FUSED score+softmax --------------------------------------------------
// Grid (32,32), 256 thr / 4 waves. Block = one 64x64 (l,m) tile, ALL 8 b.
// Wave tile 64(m) x 16(n). Per thread: 16 C/D slots x 8 b packed in 64 VGPRs.
// Round 7: issue-early LDS double-buffer over flattened (b, k0) loop —
// 32 steps, one barrier each; next step's global_load_lds issued right after
// the barrier so the loads fly during frag-load + MFMA.
__global__ __launch_bounds__(256) void score_softmax_kernel(
    const u16* __restrict__ xp, const u16* __restrict__ yp, u16* __restrict__ ATT)
{
    __shared__ __align__(16) u16 As[2][4096], Bs[2][4096];   // 64 x 64 each, x2 (32 KB)
    const int tid = threadIdx.x;
    const int w = tid >> 6, lane = tid & 63;
    const int row0 = blockIdx.x * 64, col0 = blockIdx.y * 64;
    const int wn = w * 16;
    const int fr = lane & 15, fq = lane >> 4;

    unsigned sv[NB][8];   // [b][mi*2+rp]: lo half r=rp*2, hi half r=rp*2+1

    // stage step s (s = b*4 + k-step) into buffer bu
    auto stage = [&](int s, int bu) {
        const int b = s >> 2, k0 = (s & 3) * 64;
        const u16* A = xp + (size_t)b * NL * NCI;
        const u16* B = yp + (size_t)b * NL * NCI;
#pragma unroll
        for (int pass = 0; pass < 2; ++pass) {
            const int cbase = pass * 256 + w * 64;   // wave-uniform
            const int chunk = cbase + lane;
            const int r = chunk >> 3;
            const int kc = (chunk & 7) ^ (r & 7);
            gload16(A + (size_t)(row0 + r) * NCI + k0 + kc * 8, (char*)&As[bu][0] + cbase * 16);
            gload16(B + (size_t)(col0 + r) * NCI + k0 + kc * 8, (char*)&Bs[bu][0] + cbase * 16);
        }
    };

    stage(0, 0);
    int bu = 0;
    f32x4 acc[4] = {};
    for (int s = 0; s < NB * 4; ++s) {
        __syncthreads();                       // buf[bu] ready (vmcnt drained)
        if (s + 1 < NB * 4) stage(s + 1, bu ^ 1);   // issue early, fly during compute
        f16x8 af[4][2], bf[2];
#pragma unroll
        for (int mi = 0; mi < 4; ++mi)
#pragma unroll
            for (int kt = 0; kt < 2; ++kt)
                af[mi][kt] = *(const f16x8*)&As[bu][(mi * 16 + fr) * 64 + ((kt * 4 + fq) ^ (fr & 7)) * 8];
#pragma unroll
        for (int kt = 0; kt < 2; ++kt)
            bf[kt] = *(const f16x8*)&Bs[bu][(wn + fr) * 64 + ((kt * 4 + fq) ^ (fr & 7)) * 8];
#pragma unroll
        for (int kt = 0; kt < 2; ++kt)
#pragma unroll
            for (int mi = 0; mi < 4; ++mi)
                acc[mi] = __builtin_amdgcn_mfma_f32_16x16x32_f16(af[mi][kt], bf[kt], acc[mi], 0, 0, 0);
        if ((s & 3) == 3) {                    // last k-step of this batch
            const int b = s >> 2;
#pragma unroll
            for (int mi = 0; mi < 4; ++mi) {
                sv[b][mi * 2 + 0] = (unsigned)f16b(acc[mi][0]) | ((unsigned)f16b(acc[mi][1]) << 16);
                sv[b][mi * 2 + 1] = (unsigned)f16b(acc[mi][2]) | ((unsigned)f16b(acc[mi][3]) << 16);
                acc[mi] = (f32x4){0.f, 0.f, 0.f, 0.f};
            }
        }
        bu ^= 1;
    }

    // register-only softmax over b, then write attn fp16
    const int gc = col0 + wn + fr;
#pragma unroll
    for (int mi = 0; mi < 4; ++mi) {
#pragma unroll
        for (int rp = 0; rp < 2; ++rp) {
            float v0[NB], v1[NB];
#pragma unroll
            for (int b = 0; b < NB; ++b) {
                unsigned u = sv[b][mi * 2 + rp];
                v0[b] = f16tof((u16)(u & 0xFFFF));
                v1[b] = f16tof((u16)(u >> 16));
            }
            float m0 = v0[0], m1 = v1[0];
#pragma unroll
            for (int b = 1; b < NB; ++b) { m0 = fmaxf(m0, v0[b]); m1 = fmaxf(m1, v1[b]); }
            float s0 = 0.f, s1 = 0.f;
#pragma unroll
            for (int b = 0; b < NB; ++b) {
                v0[b] = __expf(v0[b] - m0); s0 += v0[b];
                v1[b] = __expf(v1[b] - m1); s1 += v1[b];
            }
            const float i0 = 1.f / s0, i1 = 1.f / s1;
            const int gr0 = row0 + mi * 16 + fq * 4 + rp * 2;
#pragma unroll
            for (int b = 0; b < NB; ++b) {
                u16* dst = ATT + (size_t)b * NL * NL;
                dst[(size_t)gr0 * NL + gc]       = f16b(v0[b] * i0);
                dst[(size_t)(gr0 + 1) * NL + gc] = f16b(v1[b] * i1);
            }
        }
    }
}

// ---- out: out[b] = X[b] + attn[b] @ op[b], 512 thr, issue-early dbuf -------
__global__ __launch_bounds__(512) void out_kernel(
    const u16* __restrict__ ATT, const u16* __restrict__ opT,
    const float* __restrict__ X, float* __restrict__ Out)
{
    __shared__ __align__(16) u16 As[2][8192], Bs[2][8192];   // 128 x 64 each, x2
    const int tid = threadIdx.x;
    const int w = tid >> 6, lane = tid & 63;
    const int b = blockIdx.z;
    const int row0 = blockIdx.x * 128, col0 = blockIdx.y * 128;
    const u16* Aatt = ATT + (size_t)b * NL * NL;
    const u16* Bsrc = opT + (size_t)b * NC * NL;

    f32x4 acc[4][2] = {};
    const int wm = (w & 1) * 64, wn = (w >> 1) * 32;
    const int fr = lane & 15, fq = lane >> 4;

    // staging helper (as lambda): stage K-chunk k0 into buffer bu
    auto stage = [&](int k0, int bu) {
#pragma unroll
        for (int pass = 0; pass < 2; ++pass) {
            const int cbase = pass * 512 + w * 64;   // wave-uniform
            const int chunk = cbase + lane;
            const int r = chunk >> 3;
            const int kc = (chunk & 7) ^ (r & 7);
            gload16(Aatt + (size_t)(row0 + r) * NL + k0 + kc * 8, (char*)&As[bu][0] + cbase * 16);
            gload16(Bsrc + (size_t)(col0 + r) * NL + k0 + kc * 8, (char*)&Bs[bu][0] + cbase * 16);
        }
    };

    stage(0, 0);
    int bu = 0;
    for (int it = 0; it < NL / 64; ++it) {
        __syncthreads();                         // own vmcnt(0) drained -> buf[bu] ready
        if (it + 1 < NL / 64) stage((it + 1) * 64, bu ^ 1);   // issue early, fly during compute
        f16x8 af[4][2], bf[2][2];
#pragma unroll
        for (int mi = 0; mi < 4; ++mi)
#pragma unroll
            for (int kt = 0; kt < 2; ++kt)
                af[mi][kt] = *(const f16x8*)&As[bu][(wm + mi * 16 + fr) * 64 + ((kt * 4 + fq) ^ (fr & 7)) * 8];
#pragma unroll
        for (int ni = 0; ni < 2; ++ni)
#pragma unroll
            for (int kt = 0; kt < 2; ++kt)
                bf[ni][kt] = *(const f16x8*)&Bs[bu][(wn + ni * 16 + fr) * 64 + ((kt * 4 + fq) ^ (fr & 7)) * 8];
#pragma unroll
        for (int kt = 0; kt < 2; ++kt)
#pragma unroll
            for (int mi = 0; mi < 4; ++mi)
#pragma unroll
                for (int ni = 0; ni < 2; ++ni)
                    acc[mi][ni] = __builtin_amdgcn_mfma_f32_16x16x32_f16(af[mi][kt], bf[ni][kt], acc[mi][ni], 0, 0, 0);
        bu ^= 1;
    }
    const size_t ob = (size_t)b * NL * NC;
#pragma unroll
    for (int mi = 0; mi < 4; ++mi) {
        const int gr = row0 + wm + mi * 16 + fq * 4;
#pragma unroll
        for (int ni = 0; ni < 2; ++ni) {
            const int gc = col0 + wn + ni * 16 + fr;
#pragma unroll
            for (int r = 0; r < 4; ++r) {
                const size_t o = ob + (size_t)(gr + r) * NC + gc;
                Out[o] = X[o] + acc[mi][ni][r];
            }
        }
    }
}

extern "C" void kernel_launch(void* const* d_in, const int* in_sizes, int n_in,
                              void* d_out, int out_size, void* d_ws, size_t ws_size,
                              hipStream_t stream)
{
    const float* X  = (const float*)d_in[0];
    const float* Wx = (const float*)d_in[1];
    const float* bx = (const float*)d_in[2];
    const float* Wy = (const float*)d_in[3];
    const float* by = (const float*)d_in[4];
    const float* Wo = (const float*)d_in[5];
    const float* bo = (const float*)d_in[6];
    float* out = (float*)d_out;

    // Workspace (~97 MB): ATT fp16 [0,64MB); Xf16 (16MB) overlaps ATT[0:16MB) —
    // dead (proj done) before score_softmax writes ATT (stream-ordered).
    char* ws = (char*)d_ws;
    u16* ATT = (u16*)ws;
    u16* Xf  = (u16*)ws;
    char* p = ws + 67108864;
    u16* xp  = (u16*)p; p += 8388608;
    u16* yp  = (u16*)p; p += 8388608;
    u16* opT = (u16*)p; p += 16777216;
    u16* WxT = (u16*)p; p += 262144;
    u16* WyT = (u16*)p; p += 262144;
    u16* WoT = (u16*)p; p += 524288;

    cvt_x_kernel<<<4096, 256, 0, stream>>>(X, Xf);
    cvt_w_kernel<<<1024, 256, 0, stream>>>(Wx, Wy, Wo, WxT, WyT, WoT);
    proj_kernel<<<dim3(128, 8), 256, 0, stream>>>(Xf, WxT, WyT, WoT, bx, by, bo, xp, yp, opT);
    score_softmax_kernel<<<dim3(32, 32), 256, 0, stream>>>(xp, yp, ATT);
    out_kernel<<<dim3(16, 4, NB), 512, 0, stream>>>(ATT, opT, X, out);
}

// Round 2
// 225.270 us; speedup vs baseline: 1.0159x; 1.0159x over previous
//
#include <hip/hip_runtime.h>

// NonLocalBlock B=8, L=2048, C=512, CI=256 (fp32 in/out).
// Round 8:
//   - score_softmax: issue-early LDS double-buffer over the FLATTENED
//     (batch, k0) loop — now FULLY UNROLLED (#pragma unroll on the 32-step
//     loop). Round 7 left the loop rolled, so sv[b][..] was runtime-indexed
//     -> spilled to scratch (VGPR 52, +128 MB HBM scratch traffic, dur 70us).
//     Full unroll makes every sv index / stage address / buffer index a
//     compile-time constant: sv stays in VGPRs, pipeline keeps one barrier
//     per step with loads flying during compute.
//   - out_kernel unchanged (already issue-early dbuf).
//   All-fp16, XOR k-chunk swizzle (0 bank conflicts).

#define NB 8
#define NL 2048
#define NC 512
#define NCI 256

using f16x8 = __attribute__((ext_vector_type(8))) _Float16;
using f32x4 = __attribute__((ext_vector_type(4))) float;
typedef unsigned short u16;

__device__ __forceinline__ u16 f16b(float x) {
    _Float16 h = (_Float16)x;
    return __builtin_bit_cast(u16, h);
}
__device__ __forceinline__ float f16tof(u16 u) {
    return (float)__builtin_bit_cast(_Float16, u);
}
__device__ __forceinline__ void gload16(const void* g, void* l) {
    __builtin_amdgcn_global_load_lds((__attribute__((address_space(1))) void*)g,
                                     (__attribute__((address_space(3))) void*)l,
                                     16, 0, 0);
}

// ---- cvt: X fp32 -> fp16 --------------------------------------------------
__global__ __launch_bounds__(256) void cvt_x_kernel(const float* __restrict__ X,
                                                    u16* __restrict__ Xf)
{
    size_t i = (size_t)blockIdx.x * 256 + threadIdx.x;   // per 8 elements
    const float4* X4 = (const float4*)X;
    float4 a = X4[2 * i], b = X4[2 * i + 1];
    u16 o[8] = {f16b(a.x), f16b(a.y), f16b(a.z), f16b(a.w),
                f16b(b.x), f16b(b.y), f16b(b.z), f16b(b.w)};
    ((uint4*)Xf)[i] = *(const uint4*)o;
}

// ---- cvt: transpose weights to [n][k] fp16 --------------------------------
__global__ __launch_bounds__(256) void cvt_w_kernel(
    const float* __restrict__ Wx, const float* __restrict__ Wy, const float* __restrict__ Wo,
    u16* __restrict__ WxT, u16* __restrict__ WyT, u16* __restrict__ WoT)
{
    const int bid = blockIdx.x, t = threadIdx.x;
#pragma unroll
    for (int kk = 0; kk < 2; ++kk) {
        const int k = t + kk * 256;
        if (bid < 256)      WxT[(size_t)bid * NC + k] = f16b(Wx[(size_t)k * NCI + bid]);
        else if (bid < 512) WyT[(size_t)(bid - 256) * NC + k] = f16b(Wy[(size_t)k * NCI + (bid - 256)]);
        else                WoT[(size_t)(bid - 512) * NC + k] = f16b(Wo[(size_t)k * NC + (bid - 512)]);
    }
}

// ---- projections: grid (128, 8); cb 0-1 xp, 2-3 yp, 4-7 op (transposed) ----
__global__ __launch_bounds__(256) void proj_kernel(
    const u16* __restrict__ Xf,
    const u16* __restrict__ WxT, const u16* __restrict__ WyT, const u16* __restrict__ WoT,
    const float* __restrict__ bx, const float* __restrict__ by, const float* __restrict__ bo,
    u16* __restrict__ xp, u16* __restrict__ yp, u16* __restrict__ opT)
{
    __shared__ __align__(16) u16 SM[17408];   // As 8192 + Bs 8192; Ts reuse 128x136
    u16* As = SM;
    u16* Bs = SM + 8192;

    const int tid = threadIdx.x;
    const int w = tid >> 6, lane = tid & 63;
    const int row0 = blockIdx.x * 128;
    const int cb = blockIdx.y;

    const u16* W; const float* bias; int n0, path;
    if (cb < 2)      { path = 0; n0 = cb * 128;       W = WxT; bias = bx; }
    else if (cb < 4) { path = 1; n0 = (cb - 2) * 128; W = WyT; bias = by; }
    else             { path = 2; n0 = (cb - 4) * 128; W = WoT; bias = bo; }

    f32x4 acc[4][4] = {};
    const int wm = (w & 1) * 64, wn = (w >> 1) * 64;
    const int fr = lane & 15, fq = lane >> 4;

    for (int k0 = 0; k0 < NC; k0 += 64) {
#pragma unroll
        for (int pass = 0; pass < 4; ++pass) {
            const int cbase = pass * 256 + w * 64;   // wave-uniform
            const int chunk = cbase + lane;
            const int r = chunk >> 3;
            const int kc = (chunk & 7) ^ (r & 7);    // XOR-swizzled k-chunk
            gload16(Xf + (size_t)(row0 + r) * NC + k0 + kc * 8, (char*)As + cbase * 16);
            gload16(W  + (size_t)(n0  + r) * NC + k0 + kc * 8, (char*)Bs + cbase * 16);
        }
        __syncthreads();
        f16x8 a[4][2], b[4][2];
#pragma unroll
        for (int mi = 0; mi < 4; ++mi)
#pragma unroll
            for (int kt = 0; kt < 2; ++kt)
                a[mi][kt] = *(const f16x8*)&As[(wm + mi * 16 + fr) * 64 + ((kt * 4 + fq) ^ (fr & 7)) * 8];
#pragma unroll
        for (int ni = 0; ni < 4; ++ni)
#pragma unroll
            for (int kt = 0; kt < 2; ++kt)
                b[ni][kt] = *(const f16x8*)&Bs[(wn + ni * 16 + fr) * 64 + ((kt * 4 + fq) ^ (fr & 7)) * 8];
#pragma unroll
        for (int kt = 0; kt < 2; ++kt)
#pragma unroll
            for (int mi = 0; mi < 4; ++mi)
#pragma unroll
                for (int ni = 0; ni < 4; ++ni)
                    acc[mi][ni] = __builtin_amdgcn_mfma_f32_16x16x32_f16(a[mi][kt], b[ni][kt], acc[mi][ni], 0, 0, 0);
        __syncthreads();
    }

    if (path != 2) {
        u16* O = (path == 0) ? xp : yp;
#pragma unroll
        for (int mi = 0; mi < 4; ++mi) {
            const int grow = row0 + wm + mi * 16 + fq * 4;
#pragma unroll
            for (int ni = 0; ni < 4; ++ni) {
                const int gcol = n0 + wn + ni * 16 + fr;
                const float bv = bias[gcol];
#pragma unroll
                for (int r = 0; r < 4; ++r)
                    O[(size_t)(grow + r) * NCI + gcol] = f16b(acc[mi][ni][r] + bv);
            }
        }
    } else {
        u16* Ts = SM;   // 128 x 136 fp16 transpose staging
#pragma unroll
        for (int mi = 0; mi < 4; ++mi) {
            const int mb = wm + mi * 16 + fq * 4;
#pragma unroll
            for (int ni = 0; ni < 4; ++ni) {
                const int nl_ = wn + ni * 16 + fr;
                const float bv = bias[n0 + nl_];
#pragma unroll
                for (int r = 0; r < 4; ++r)
                    Ts[nl_ * 136 + mb + r] = f16b(acc[mi][ni][r] + bv);
            }
        }
        __syncthreads();
        const int b = row0 >> 11, m0 = row0 & 2047;
        u16* dst = opT + (size_t)b * NC * NL + (size_t)n0 * NL + m0;
        for (int i = tid; i < 128 * 16; i += 256) {
            const int c = i >> 4, ch = i & 15;
            uint4 v = *(const uint4*)&Ts[c * 136 + ch * 8];
            *(uint4*)&dst[(size_t)c * NL + ch * 8] = v;
        }
    }
}

// ---- FUSED score+softmax --------------------------------------------------
// Grid (32,32), 256 thr / 4 waves. Block = one 64x64 (l,m) tile, ALL 8 b.
// Wave tile 64(m) x 16(n). Per thread: 16 C/D slots x 8 b packed in 64 VGPRs.
// Round 8: issue-early LDS double-buffer, 32 steps FULLY UNROLLED so all
// sv/stage/buffer indices are compile-time constants (no scratch spill).
__global__ __launch_bounds__(256) void score_softmax_kernel(
    const u16* __restrict__ xp, const u16* __restrict__ yp, u16* __restrict__ ATT)
{
    __shared__ __align__(16) u16 As[2][4096], Bs[2][4096];   // 64 x 64 each, x2 (32 KB)
    const int tid = threadIdx.x;
    const int w = tid >> 6, lane = tid & 63;
    const int row0 = blockIdx.x * 64, col0 = blockIdx.y * 64;
    const int wn = w * 16;
    const int fr = lane & 15, fq = lane >> 4;

    unsigned sv[NB][8];   // [b][mi*2+rp]: lo half r=rp*2, hi half r=rp*2+1

    // stage step s (s = b*4 + k-step) into buffer bu (s, bu compile-time)
    auto stage = [&](int s, int bu) {
        const int b = s >> 2, k0 = (s & 3) * 64;
        const u16* A = xp + (size_t)b * NL * NCI;
        const u16* B = yp + (size_t)b * NL * NCI;
#pragma unroll
        for (int pass = 0; pass < 2; ++pass) {
            const int cbase = pass * 256 + w * 64;   // wave-uniform
            const int chunk = cbase + lane;
            const int r = chunk >> 3;
            const int kc = (chunk & 7) ^ (r & 7);
            gload16(A + (size_t)(row0 + r) * NCI + k0 + kc * 8, (char*)&As[bu][0] + cbase * 16);
            gload16(B + (size_t)(col0 + r) * NCI + k0 + kc * 8, (char*)&Bs[bu][0] + cbase * 16);
        }
    };

    stage(0, 0);
    f32x4 acc[4] = {};
#pragma unroll
    for (int s = 0; s < NB * 4; ++s) {
        const int bu = s & 1;                  // compile-time after unroll
        __syncthreads();                       // buf[bu] ready (vmcnt drained)
        if (s + 1 < NB * 4) stage(s + 1, bu ^ 1);   // issue early, fly during compute
        f16x8 af[4][2], bf[2];
#pragma unroll
        for (int mi = 0; mi < 4; ++mi)
#pragma unroll
            for (int kt = 0; kt < 2; ++kt)
                af[mi][kt] = *(const f16x8*)&As[bu][(mi * 16 + fr) * 64 + ((kt * 4 + fq) ^ (fr & 7)) * 8];
#pragma unroll
        for (int kt = 0; kt < 2; ++kt)
            bf[kt] = *(const f16x8*)&Bs[bu][(wn + fr) * 64 + ((kt * 4 + fq) ^ (fr & 7)) * 8];
#pragma unroll
        for (int kt = 0; kt < 2; ++kt)
#pragma unroll
            for (int mi = 0; mi < 4; ++mi)
                acc[mi] = __builtin_amdgcn_mfma_f32_16x16x32_f16(af[mi][kt], bf[kt], acc[mi], 0, 0, 0);
        if ((s & 3) == 3) {                    // last k-step of this batch
            const int b = s >> 2;              // compile-time after unroll
#pragma unroll
            for (int mi = 0; mi < 4; ++mi) {
                sv[b][mi * 2 + 0] = (unsigned)f16b(acc[mi][0]) | ((unsigned)f16b(acc[mi][1]) << 16);
                sv[b][mi * 2 + 1] = (unsigned)f16b(acc[mi][2]) | ((unsigned)f16b(acc[mi][3]) << 16);
                acc[mi] = (f32x4){0.f, 0.f, 0.f, 0.f};
            }
        }
    }

    // register-only softmax over b, then write attn fp16
    const int gc = col0 + wn + fr;
#pragma unroll
    for (int mi = 0; mi < 4; ++mi) {
#pragma unroll
        for (int rp = 0; rp < 2; ++rp) {
            float v0[NB], v1[NB];
#pragma unroll
            for (int b = 0; b < NB; ++b) {
                unsigned u = sv[b][mi * 2 + rp];
                v0[b] = f16tof((u16)(u & 0xFFFF));
                v1[b] = f16tof((u16)(u >> 16));
            }
            float m0 = v0[0], m1 = v1[0];
#pragma unroll
            for (int b = 1; b < NB; ++b) { m0 = fmaxf(m0, v0[b]); m1 = fmaxf(m1, v1[b]); }
            float s0 = 0.f, s1 = 0.f;
#pragma unroll
            for (int b = 0; b < NB; ++b) {
                v0[b] = __expf(v0[b] - m0); s0 += v0[b];
                v1[b] = __expf(v1[b] - m1); s1 += v1[b];
            }
            const float i0 = 1.f / s0, i1 = 1.f / s1;
            const int gr0 = row0 + mi * 16 + fq * 4 + rp * 2;
#pragma unroll
            for (int b = 0; b < NB; ++b) {
                u16* dst = ATT + (size_t)b * NL * NL;
                dst[(size_t)gr0 * NL + gc]       = f16b(v0[b] * i0);
                dst[(size_t)(gr0 + 1) * NL + gc] = f16b(v1[b] * i1);
            }
        }
    }
}

// ---- out: out[b] = X[b] + attn[b] @ op[b], 512 thr, issue-early dbuf -------
__global__ __launch_bounds__(512) void out_kernel(
    const u16* __restrict__ ATT, const u16* __restrict__ opT,
    const float* __restrict__ X, float* __restrict__ Out)
{
    __shared__ __align__(16) u16 As[2][8192], Bs[2][8192];   // 128 x 64 each, x2
    const int tid = threadIdx.x;
    const int w = tid >> 6, lane = tid & 63;
    const int b = blockIdx.z;
    const int row0 = blockIdx.x * 128, col0 = blockIdx.y * 128;
    const u16* Aatt = ATT + (size_t)b * NL * NL;
    const u16* Bsrc = opT + (size_t)b * NC * NL;

    f32x4 acc[4][2] = {};
    const int wm = (w & 1) * 64, wn = (w >> 1) * 32;
    const int fr = lane & 15, fq = lane >> 4;

    // staging helper (as lambda): stage K-chunk k0 into buffer bu
    auto stage = [&](int k0, int bu) {
#pragma unroll
        for (int pass = 0; pass < 2; ++pass) {
            const int cbase = pass * 512 + w * 64;   // wave-uniform
            const int chunk = cbase + lane;
            const int r = chunk >> 3;
            const int kc = (chunk & 7) ^ (r & 7);
            gload16(Aatt + (size_t)(row0 + r) * NL + k0 + kc * 8, (char*)&As[bu][0] + cbase * 16);
            gload16(Bsrc + (size_t)(col0 + r) * NL + k0 + kc * 8, (char*)&Bs[bu][0] + cbase * 16);
        }
    };

    stage(0, 0);
    int bu = 0;
    for (int it = 0; it < NL / 64; ++it) {
        __syncthreads();                         // own vmcnt(0) drained -> buf[bu] ready
        if (it + 1 < NL / 64) stage((it + 1) * 64, bu ^ 1);   // issue early, fly during compute
        f16x8 af[4][2], bf[2][2];
#pragma unroll
        for (int mi = 0; mi < 4; ++mi)
#pragma unroll
            for (int kt = 0; kt < 2; ++kt)
                af[mi][kt] = *(const f16x8*)&As[bu][(wm + mi * 16 + fr) * 64 + ((kt * 4 + fq) ^ (fr & 7)) * 8];
#pragma unroll
        for (int ni = 0; ni < 2; ++ni)
#pragma unroll
            for (int kt = 0; kt < 2; ++kt)
                bf[ni][kt] = *(const f16x8*)&Bs[bu][(wn + ni * 16 + fr) * 64 + ((kt * 4 + fq) ^ (fr & 7)) * 8];
#pragma unroll
        for (int kt = 0; kt < 2; ++kt)
#pragma unroll
            for (int mi = 0; mi < 4; ++mi)
#pragma unroll
                for (int ni = 0; ni < 2; ++ni)
                    acc[mi][ni] = __builtin_amdgcn_mfma_f32_16x16x32_f16(af[mi][kt], bf[ni][kt], acc[mi][ni], 0, 0, 0);
        bu ^= 1;
    }
    const size_t ob = (size_t)b * NL * NC;
#pragma unroll
    for (int mi = 0; mi < 4; ++mi) {
        const int gr = row0 + wm + mi * 16 + fq * 4;
#pragma unroll
        for (int ni = 0; ni < 2; ++ni) {
            const int gc = col0 + wn + ni * 16 + fr;
#pragma unroll
            for (int r = 0; r < 4; ++r) {
                const size_t o = ob + (size_t)(gr + r) * NC + gc;
                Out[o] = X[o] + acc[mi][ni][r];
            }
        }
    }
}

extern "C" void kernel_launch(void* const* d_in, const int* in_sizes, int n_in,
                              void* d_out, int out_size, void* d_ws, size_t ws_size,
                              hipStream_t stream)
{
    const float* X  = (const float*)d_in[0];
    const float* Wx = (const float*)d_in[1];
    const float* bx = (const float*)d_in[2];
    const float* Wy = (const float*)d_in[3];
    const float* by = (const float*)d_in[4];
    const float* Wo = (const float*)d_in[5];
    const float* bo = (const float*)d_in[6];
    float* out = (float*)d_out;

    // Workspace (~97 MB): ATT fp16 [0,64MB); Xf16 (16MB) overlaps ATT[0:16MB) —
    // dead (proj done) before score_softmax writes ATT (stream-ordered).
    char* ws = (char*)d_ws;
    u16* ATT = (u16*)ws;
    u16* Xf  = (u16*)ws;
    char* p = ws + 67108864;
    u16* xp  = (u16*)p; p += 8388608;
    u16* yp  = (u16*)p; p += 8388608;
    u16* opT = (u16*)p; p += 16777216;
    u16* WxT = (u16*)p; p += 262144;
    u16* WyT = (u16*)p; p += 262144;
    u16* WoT = (u16*)p; p += 524288;

    cvt_x_kernel<<<4096, 256, 0, stream>>>(X, Xf);
    cvt_w_kernel<<<1024, 256, 0, stream>>>(Wx, Wy, Wo, WxT, WyT, WoT);
    proj_kernel<<<dim3(128, 8), 256, 0, stream>>>(Xf, WxT, WyT, WoT, bx, by, bo, xp, yp, opT);
    score_softmax_kernel<<<dim3(32, 32), 256, 0, stream>>>(xp, yp, ATT);
    out_kernel<<<dim3(16, 4, NB), 512, 0, stream>>>(ATT, opT, X, out);
}

// Round 3
// 208.098 us; speedup vs baseline: 1.0997x; 1.0825x over previous
//
#include <hip/hip_runtime.h>

// NonLocalBlock B=8, L=2048, C=512, CI=256 (fp32 in/out).
// Round 9:
//   - score_softmax: BACK TO SERIAL round-6 structure (both pipelined variants
//     r7/r8 regressed: 70/74 us vs 60 us serial — __syncthreads vmcnt drain
//     defeats source-level pipelining, per m131-m140). Change: BK 64 -> 128.
//     16 big stages (8 gload16/thread) instead of 32 small ones -> half the
//     full-latency barrier drains; LDS 32 KB keeps 4-5 blocks/CU residency.
//     Frag reads as kk-loop (5 frags live) to hold VGPR near round-6 level.
//   - out_kernel unchanged (issue-early dbuf, part of the 216.8 us baseline).
//   All-fp16, XOR k-chunk swizzle (0 bank conflicts).

#define NB 8
#define NL 2048
#define NC 512
#define NCI 256

using f16x8 = __attribute__((ext_vector_type(8))) _Float16;
using f32x4 = __attribute__((ext_vector_type(4))) float;
typedef unsigned short u16;

__device__ __forceinline__ u16 f16b(float x) {
    _Float16 h = (_Float16)x;
    return __builtin_bit_cast(u16, h);
}
__device__ __forceinline__ float f16tof(u16 u) {
    return (float)__builtin_bit_cast(_Float16, u);
}
__device__ __forceinline__ void gload16(const void* g, void* l) {
    __builtin_amdgcn_global_load_lds((__attribute__((address_space(1))) void*)g,
                                     (__attribute__((address_space(3))) void*)l,
                                     16, 0, 0);
}

// ---- cvt: X fp32 -> fp16 --------------------------------------------------
__global__ __launch_bounds__(256) void cvt_x_kernel(const float* __restrict__ X,
                                                    u16* __restrict__ Xf)
{
    size_t i = (size_t)blockIdx.x * 256 + threadIdx.x;   // per 8 elements
    const float4* X4 = (const float4*)X;
    float4 a = X4[2 * i], b = X4[2 * i + 1];
    u16 o[8] = {f16b(a.x), f16b(a.y), f16b(a.z), f16b(a.w),
                f16b(b.x), f16b(b.y), f16b(b.z), f16b(b.w)};
    ((uint4*)Xf)[i] = *(const uint4*)o;
}

// ---- cvt: transpose weights to [n][k] fp16 --------------------------------
__global__ __launch_bounds__(256) void cvt_w_kernel(
    const float* __restrict__ Wx, const float* __restrict__ Wy, const float* __restrict__ Wo,
    u16* __restrict__ WxT, u16* __restrict__ WyT, u16* __restrict__ WoT)
{
    const int bid = blockIdx.x, t = threadIdx.x;
#pragma unroll
    for (int kk = 0; kk < 2; ++kk) {
        const int k = t + kk * 256;
        if (bid < 256)      WxT[(size_t)bid * NC + k] = f16b(Wx[(size_t)k * NCI + bid]);
        else if (bid < 512) WyT[(size_t)(bid - 256) * NC + k] = f16b(Wy[(size_t)k * NCI + (bid - 256)]);
        else                WoT[(size_t)(bid - 512) * NC + k] = f16b(Wo[(size_t)k * NC + (bid - 512)]);
    }
}

// ---- projections: grid (128, 8); cb 0-1 xp, 2-3 yp, 4-7 op (transposed) ----
__global__ __launch_bounds__(256) void proj_kernel(
    const u16* __restrict__ Xf,
    const u16* __restrict__ WxT, const u16* __restrict__ WyT, const u16* __restrict__ WoT,
    const float* __restrict__ bx, const float* __restrict__ by, const float* __restrict__ bo,
    u16* __restrict__ xp, u16* __restrict__ yp, u16* __restrict__ opT)
{
    __shared__ __align__(16) u16 SM[17408];   // As 8192 + Bs 8192; Ts reuse 128x136
    u16* As = SM;
    u16* Bs = SM + 8192;

    const int tid = threadIdx.x;
    const int w = tid >> 6, lane = tid & 63;
    const int row0 = blockIdx.x * 128;
    const int cb = blockIdx.y;

    const u16* W; const float* bias; int n0, path;
    if (cb < 2)      { path = 0; n0 = cb * 128;       W = WxT; bias = bx; }
    else if (cb < 4) { path = 1; n0 = (cb - 2) * 128; W = WyT; bias = by; }
    else             { path = 2; n0 = (cb - 4) * 128; W = WoT; bias = bo; }

    f32x4 acc[4][4] = {};
    const int wm = (w & 1) * 64, wn = (w >> 1) * 64;
    const int fr = lane & 15, fq = lane >> 4;

    for (int k0 = 0; k0 < NC; k0 += 64) {
#pragma unroll
        for (int pass = 0; pass < 4; ++pass) {
            const int cbase = pass * 256 + w * 64;   // wave-uniform
            const int chunk = cbase + lane;
            const int r = chunk >> 3;
            const int kc = (chunk & 7) ^ (r & 7);    // XOR-swizzled k-chunk
            gload16(Xf + (size_t)(row0 + r) * NC + k0 + kc * 8, (char*)As + cbase * 16);
            gload16(W  + (size_t)(n0  + r) * NC + k0 + kc * 8, (char*)Bs + cbase * 16);
        }
        __syncthreads();
        f16x8 a[4][2], b[4][2];
#pragma unroll
        for (int mi = 0; mi < 4; ++mi)
#pragma unroll
            for (int kt = 0; kt < 2; ++kt)
                a[mi][kt] = *(const f16x8*)&As[(wm + mi * 16 + fr) * 64 + ((kt * 4 + fq) ^ (fr & 7)) * 8];
#pragma unroll
        for (int ni = 0; ni < 4; ++ni)
#pragma unroll
            for (int kt = 0; kt < 2; ++kt)
                b[ni][kt] = *(const f16x8*)&Bs[(wn + ni * 16 + fr) * 64 + ((kt * 4 + fq) ^ (fr & 7)) * 8];
#pragma unroll
        for (int kt = 0; kt < 2; ++kt)
#pragma unroll
            for (int mi = 0; mi < 4; ++mi)
#pragma unroll
                for (int ni = 0; ni < 4; ++ni)
                    acc[mi][ni] = __builtin_amdgcn_mfma_f32_16x16x32_f16(a[mi][kt], b[ni][kt], acc[mi][ni], 0, 0, 0);
        __syncthreads();
    }

    if (path != 2) {
        u16* O = (path == 0) ? xp : yp;
#pragma unroll
        for (int mi = 0; mi < 4; ++mi) {
            const int grow = row0 + wm + mi * 16 + fq * 4;
#pragma unroll
            for (int ni = 0; ni < 4; ++ni) {
                const int gcol = n0 + wn + ni * 16 + fr;
                const float bv = bias[gcol];
#pragma unroll
                for (int r = 0; r < 4; ++r)
                    O[(size_t)(grow + r) * NCI + gcol] = f16b(acc[mi][ni][r] + bv);
            }
        }
    } else {
        u16* Ts = SM;   // 128 x 136 fp16 transpose staging
#pragma unroll
        for (int mi = 0; mi < 4; ++mi) {
            const int mb = wm + mi * 16 + fq * 4;
#pragma unroll
            for (int ni = 0; ni < 4; ++ni) {
                const int nl_ = wn + ni * 16 + fr;
                const float bv = bias[n0 + nl_];
#pragma unroll
                for (int r = 0; r < 4; ++r)
                    Ts[nl_ * 136 + mb + r] = f16b(acc[mi][ni][r] + bv);
            }
        }
        __syncthreads();
        const int b = row0 >> 11, m0 = row0 & 2047;
        u16* dst = opT + (size_t)b * NC * NL + (size_t)n0 * NL + m0;
        for (int i = tid; i < 128 * 16; i += 256) {
            const int c = i >> 4, ch = i & 15;
            uint4 v = *(const uint4*)&Ts[c * 136 + ch * 8];
            *(uint4*)&dst[(size_t)c * NL + ch * 8] = v;
        }
    }
}

// ---- FUSED score+softmax --------------------------------------------------
// Grid (32,32), 256 thr / 4 waves. Block = one 64x64 (l,m) tile, ALL 8 b.
// Wave tile 64(m) x 16(n). Per thread: 16 C/D slots x 8 b packed in 64 VGPRs.
// Round 9: serial stages (round-6 structure), BK=128: 16 stages of
// 8 gload16/thread instead of 32 of 4 -> half the barrier latency drains.
__global__ __launch_bounds__(256) void score_softmax_kernel(
    const u16* __restrict__ xp, const u16* __restrict__ yp, u16* __restrict__ ATT)
{
    __shared__ __align__(16) u16 As[8192], Bs[8192];   // 64 x 128 each (32 KB)
    const int tid = threadIdx.x;
    const int w = tid >> 6, lane = tid & 63;
    const int row0 = blockIdx.x * 64, col0 = blockIdx.y * 64;
    const int wn = w * 16;
    const int fr = lane & 15, fq = lane >> 4;

    unsigned sv[NB][8];   // [b][mi*2+rp]: lo half r=rp*2, hi half r=rp*2+1

#pragma unroll
    for (int b = 0; b < NB; ++b) {
        const u16* A = xp + (size_t)b * NL * NCI;
        const u16* B = yp + (size_t)b * NL * NCI;
        f32x4 acc[4] = {};
#pragma unroll
        for (int h = 0; h < 2; ++h) {
            const int k0 = h * 128;
            // stage 64x128 A and B tiles (16 KB each, 4 passes)
#pragma unroll
            for (int pass = 0; pass < 4; ++pass) {
                const int cbase = pass * 256 + w * 64;   // wave-uniform
                const int chunk = cbase + lane;
                const int r = chunk >> 4;                 // row 0..63
                const int kc = (chunk & 15) ^ (r & 7);    // XOR-swizzled 16B chunk
                gload16(A + (size_t)(row0 + r) * NCI + k0 + kc * 8, (char*)As + cbase * 16);
                gload16(B + (size_t)(col0 + r) * NCI + k0 + kc * 8, (char*)Bs + cbase * 16);
            }
            __syncthreads();
#pragma unroll
            for (int kk = 0; kk < 4; ++kk) {
                f16x8 af[4], bf;
                bf = *(const f16x8*)&Bs[(wn + fr) * 128 + ((kk * 4 + fq) ^ (fr & 7)) * 8];
#pragma unroll
                for (int mi = 0; mi < 4; ++mi)
                    af[mi] = *(const f16x8*)&As[(mi * 16 + fr) * 128 + ((kk * 4 + fq) ^ (fr & 7)) * 8];
#pragma unroll
                for (int mi = 0; mi < 4; ++mi)
                    acc[mi] = __builtin_amdgcn_mfma_f32_16x16x32_f16(af[mi], bf, acc[mi], 0, 0, 0);
            }
            __syncthreads();
        }
#pragma unroll
        for (int mi = 0; mi < 4; ++mi) {
            sv[b][mi * 2 + 0] = (unsigned)f16b(acc[mi][0]) | ((unsigned)f16b(acc[mi][1]) << 16);
            sv[b][mi * 2 + 1] = (unsigned)f16b(acc[mi][2]) | ((unsigned)f16b(acc[mi][3]) << 16);
        }
    }

    // register-only softmax over b, then write attn fp16
    const int gc = col0 + wn + fr;
#pragma unroll
    for (int mi = 0; mi < 4; ++mi) {
#pragma unroll
        for (int rp = 0; rp < 2; ++rp) {
            float v0[NB], v1[NB];
#pragma unroll
            for (int b = 0; b < NB; ++b) {
                unsigned u = sv[b][mi * 2 + rp];
                v0[b] = f16tof((u16)(u & 0xFFFF));
                v1[b] = f16tof((u16)(u >> 16));
            }
            float m0 = v0[0], m1 = v1[0];
#pragma unroll
            for (int b = 1; b < NB; ++b) { m0 = fmaxf(m0, v0[b]); m1 = fmaxf(m1, v1[b]); }
            float s0 = 0.f, s1 = 0.f;
#pragma unroll
            for (int b = 0; b < NB; ++b) {
                v0[b] = __expf(v0[b] - m0); s0 += v0[b];
                v1[b] = __expf(v1[b] - m1); s1 += v1[b];
            }
            const float i0 = 1.f / s0, i1 = 1.f / s1;
            const int gr0 = row0 + mi * 16 + fq * 4 + rp * 2;
#pragma unroll
            for (int b = 0; b < NB; ++b) {
                u16* dst = ATT + (size_t)b * NL * NL;
                dst[(size_t)gr0 * NL + gc]       = f16b(v0[b] * i0);
                dst[(size_t)(gr0 + 1) * NL + gc] = f16b(v1[b] * i1);
            }
        }
    }
}

// ---- out: out[b] = X[b] + attn[b] @ op[b], 512 thr, issue-early dbuf -------
__global__ __launch_bounds__(512) void out_kernel(
    const u16* __restrict__ ATT, const u16* __restrict__ opT,
    const float* __restrict__ X, float* __restrict__ Out)
{
    __shared__ __align__(16) u16 As[2][8192], Bs[2][8192];   // 128 x 64 each, x2
    const int tid = threadIdx.x;
    const int w = tid >> 6, lane = tid & 63;
    const int b = blockIdx.z;
    const int row0 = blockIdx.x * 128, col0 = blockIdx.y * 128;
    const u16* Aatt = ATT + (size_t)b * NL * NL;
    const u16* Bsrc = opT + (size_t)b * NC * NL;

    f32x4 acc[4][2] = {};
    const int wm = (w & 1) * 64, wn = (w >> 1) * 32;
    const int fr = lane & 15, fq = lane >> 4;

    // staging helper (as lambda): stage K-chunk k0 into buffer bu
    auto stage = [&](int k0, int bu) {
#pragma unroll
        for (int pass = 0; pass < 2; ++pass) {
            const int cbase = pass * 512 + w * 64;   // wave-uniform
            const int chunk = cbase + lane;
            const int r = chunk >> 3;
            const int kc = (chunk & 7) ^ (r & 7);
            gload16(Aatt + (size_t)(row0 + r) * NL + k0 + kc * 8, (char*)&As[bu][0] + cbase * 16);
            gload16(Bsrc + (size_t)(col0 + r) * NL + k0 + kc * 8, (char*)&Bs[bu][0] + cbase * 16);
        }
    };

    stage(0, 0);
    int bu = 0;
    for (int it = 0; it < NL / 64; ++it) {
        __syncthreads();                         // own vmcnt(0) drained -> buf[bu] ready
        if (it + 1 < NL / 64) stage((it + 1) * 64, bu ^ 1);   // issue early, fly during compute
        f16x8 af[4][2], bf[2][2];
#pragma unroll
        for (int mi = 0; mi < 4; ++mi)
#pragma unroll
            for (int kt = 0; kt < 2; ++kt)
                af[mi][kt] = *(const f16x8*)&As[bu][(wm + mi * 16 + fr) * 64 + ((kt * 4 + fq) ^ (fr & 7)) * 8];
#pragma unroll
        for (int ni = 0; ni < 2; ++ni)
#pragma unroll
            for (int kt = 0; kt < 2; ++kt)
                bf[ni][kt] = *(const f16x8*)&Bs[bu][(wn + ni * 16 + fr) * 64 + ((kt * 4 + fq) ^ (fr & 7)) * 8];
#pragma unroll
        for (int kt = 0; kt < 2; ++kt)
#pragma unroll
            for (int mi = 0; mi < 4; ++mi)
#pragma unroll
                for (int ni = 0; ni < 2; ++ni)
                    acc[mi][ni] = __builtin_amdgcn_mfma_f32_16x16x32_f16(af[mi][kt], bf[ni][kt], acc[mi][ni], 0, 0, 0);
        bu ^= 1;
    }
    const size_t ob = (size_t)b * NL * NC;
#pragma unroll
    for (int mi = 0; mi < 4; ++mi) {
        const int gr = row0 + wm + mi * 16 + fq * 4;
#pragma unroll
        for (int ni = 0; ni < 2; ++ni) {
            const int gc = col0 + wn + ni * 16 + fr;
#pragma unroll
            for (int r = 0; r < 4; ++r) {
                const size_t o = ob + (size_t)(gr + r) * NC + gc;
                Out[o] = X[o] + acc[mi][ni][r];
            }
        }
    }
}

extern "C" void kernel_launch(void* const* d_in, const int* in_sizes, int n_in,
                              void* d_out, int out_size, void* d_ws, size_t ws_size,
                              hipStream_t stream)
{
    const float* X  = (const float*)d_in[0];
    const float* Wx = (const float*)d_in[1];
    const float* bx = (const float*)d_in[2];
    const float* Wy = (const float*)d_in[3];
    const float* by = (const float*)d_in[4];
    const float* Wo = (const float*)d_in[5];
    const float* bo = (const float*)d_in[6];
    float* out = (float*)d_out;

    // Workspace (~97 MB): ATT fp16 [0,64MB); Xf16 (16MB) overlaps ATT[0:16MB) —
    // dead (proj done) before score_softmax writes ATT (stream-ordered).
    char* ws = (char*)d_ws;
    u16* ATT = (u16*)ws;
    u16* Xf  = (u16*)ws;
    char* p = ws + 67108864;
    u16* xp  = (u16*)p; p += 8388608;
    u16* yp  = (u16*)p; p += 8388608;
    u16* opT = (u16*)p; p += 16777216;
    u16* WxT = (u16*)p; p += 262144;
    u16* WyT = (u16*)p; p += 262144;
    u16* WoT = (u16*)p; p += 524288;

    cvt_x_kernel<<<4096, 256, 0, stream>>>(X, Xf);
    cvt_w_kernel<<<1024, 256, 0, stream>>>(Wx, Wy, Wo, WxT, WyT, WoT);
    proj_kernel<<<dim3(128, 8), 256, 0, stream>>>(Xf, WxT, WyT, WoT, bx, by, bo, xp, yp, opT);
    score_softmax_kernel<<<dim3(32, 32), 256, 0, stream>>>(xp, yp, ATT);
    out_kernel<<<dim3(16, 4, NB), 512, 0, stream>>>(ATT, opT, X, out);
}

// Round 4
// 205.972 us; speedup vs baseline: 1.1110x; 1.0103x over previous
//
#include <hip/hip_runtime.h>

// NonLocalBlock B=8, L=2048, C=512, CI=256 (fp32 in/out).
// Round 10:
//   - score_softmax: keep BK=128 (16 big stages, r9 win 60->54us) but store
//     each 64x128 tile as TWO stacked 64x64-u16 half-tiles (row' = kh*64+r,
//     128B row stride). gload_lds dest stays linear in chunk; the source
//     address absorbs the remap. ds_read pattern is then byte-identical to
//     round 6's measured-zero-conflict geometry (r9's 256B-row layout showed
//     5.24M SQ_LDS_BANK_CONFLICT).
//   - out_kernel unchanged (issue-early dbuf).
//   All-fp16, XOR k-chunk swizzle.

#define NB 8
#define NL 2048
#define NC 512
#define NCI 256

using f16x8 = __attribute__((ext_vector_type(8))) _Float16;
using f32x4 = __attribute__((ext_vector_type(4))) float;
typedef unsigned short u16;

__device__ __forceinline__ u16 f16b(float x) {
    _Float16 h = (_Float16)x;
    return __builtin_bit_cast(u16, h);
}
__device__ __forceinline__ float f16tof(u16 u) {
    return (float)__builtin_bit_cast(_Float16, u);
}
__device__ __forceinline__ void gload16(const void* g, void* l) {
    __builtin_amdgcn_global_load_lds((__attribute__((address_space(1))) void*)g,
                                     (__attribute__((address_space(3))) void*)l,
                                     16, 0, 0);
}

// ---- cvt: X fp32 -> fp16 --------------------------------------------------
__global__ __launch_bounds__(256) void cvt_x_kernel(const float* __restrict__ X,
                                                    u16* __restrict__ Xf)
{
    size_t i = (size_t)blockIdx.x * 256 + threadIdx.x;   // per 8 elements
    const float4* X4 = (const float4*)X;
    float4 a = X4[2 * i], b = X4[2 * i + 1];
    u16 o[8] = {f16b(a.x), f16b(a.y), f16b(a.z), f16b(a.w),
                f16b(b.x), f16b(b.y), f16b(b.z), f16b(b.w)};
    ((uint4*)Xf)[i] = *(const uint4*)o;
}

// ---- cvt: transpose weights to [n][k] fp16 --------------------------------
__global__ __launch_bounds__(256) void cvt_w_kernel(
    const float* __restrict__ Wx, const float* __restrict__ Wy, const float* __restrict__ Wo,
    u16* __restrict__ WxT, u16* __restrict__ WyT, u16* __restrict__ WoT)
{
    const int bid = blockIdx.x, t = threadIdx.x;
#pragma unroll
    for (int kk = 0; kk < 2; ++kk) {
        const int k = t + kk * 256;
        if (bid < 256)      WxT[(size_t)bid * NC + k] = f16b(Wx[(size_t)k * NCI + bid]);
        else if (bid < 512) WyT[(size_t)(bid - 256) * NC + k] = f16b(Wy[(size_t)k * NCI + (bid - 256)]);
        else                WoT[(size_t)(bid - 512) * NC + k] = f16b(Wo[(size_t)k * NC + (bid - 512)]);
    }
}

// ---- projections: grid (128, 8); cb 0-1 xp, 2-3 yp, 4-7 op (transposed) ----
__global__ __launch_bounds__(256) void proj_kernel(
    const u16* __restrict__ Xf,
    const u16* __restrict__ WxT, const u16* __restrict__ WyT, const u16* __restrict__ WoT,
    const float* __restrict__ bx, const float* __restrict__ by, const float* __restrict__ bo,
    u16* __restrict__ xp, u16* __restrict__ yp, u16* __restrict__ opT)
{
    __shared__ __align__(16) u16 SM[17408];   // As 8192 + Bs 8192; Ts reuse 128x136
    u16* As = SM;
    u16* Bs = SM + 8192;

    const int tid = threadIdx.x;
    const int w = tid >> 6, lane = tid & 63;
    const int row0 = blockIdx.x * 128;
    const int cb = blockIdx.y;

    const u16* W; const float* bias; int n0, path;
    if (cb < 2)      { path = 0; n0 = cb * 128;       W = WxT; bias = bx; }
    else if (cb < 4) { path = 1; n0 = (cb - 2) * 128; W = WyT; bias = by; }
    else             { path = 2; n0 = (cb - 4) * 128; W = WoT; bias = bo; }

    f32x4 acc[4][4] = {};
    const int wm = (w & 1) * 64, wn = (w >> 1) * 64;
    const int fr = lane & 15, fq = lane >> 4;

    for (int k0 = 0; k0 < NC; k0 += 64) {
#pragma unroll
        for (int pass = 0; pass < 4; ++pass) {
            const int cbase = pass * 256 + w * 64;   // wave-uniform
            const int chunk = cbase + lane;
            const int r = chunk >> 3;
            const int kc = (chunk & 7) ^ (r & 7);    // XOR-swizzled k-chunk
            gload16(Xf + (size_t)(row0 + r) * NC + k0 + kc * 8, (char*)As + cbase * 16);
            gload16(W  + (size_t)(n0  + r) * NC + k0 + kc * 8, (char*)Bs + cbase * 16);
        }
        __syncthreads();
        f16x8 a[4][2], b[4][2];
#pragma unroll
        for (int mi = 0; mi < 4; ++mi)
#pragma unroll
            for (int kt = 0; kt < 2; ++kt)
                a[mi][kt] = *(const f16x8*)&As[(wm + mi * 16 + fr) * 64 + ((kt * 4 + fq) ^ (fr & 7)) * 8];
#pragma unroll
        for (int ni = 0; ni < 4; ++ni)
#pragma unroll
            for (int kt = 0; kt < 2; ++kt)
                b[ni][kt] = *(const f16x8*)&Bs[(wn + ni * 16 + fr) * 64 + ((kt * 4 + fq) ^ (fr & 7)) * 8];
#pragma unroll
        for (int kt = 0; kt < 2; ++kt)
#pragma unroll
            for (int mi = 0; mi < 4; ++mi)
#pragma unroll
                for (int ni = 0; ni < 4; ++ni)
                    acc[mi][ni] = __builtin_amdgcn_mfma_f32_16x16x32_f16(a[mi][kt], b[ni][kt], acc[mi][ni], 0, 0, 0);
        __syncthreads();
    }

    if (path != 2) {
        u16* O = (path == 0) ? xp : yp;
#pragma unroll
        for (int mi = 0; mi < 4; ++mi) {
            const int grow = row0 + wm + mi * 16 + fq * 4;
#pragma unroll
            for (int ni = 0; ni < 4; ++ni) {
                const int gcol = n0 + wn + ni * 16 + fr;
                const float bv = bias[gcol];
#pragma unroll
                for (int r = 0; r < 4; ++r)
                    O[(size_t)(grow + r) * NCI + gcol] = f16b(acc[mi][ni][r] + bv);
            }
        }
    } else {
        u16* Ts = SM;   // 128 x 136 fp16 transpose staging
#pragma unroll
        for (int mi = 0; mi < 4; ++mi) {
            const int mb = wm + mi * 16 + fq * 4;
#pragma unroll
            for (int ni = 0; ni < 4; ++ni) {
                const int nl_ = wn + ni * 16 + fr;
                const float bv = bias[n0 + nl_];
#pragma unroll
                for (int r = 0; r < 4; ++r)
                    Ts[nl_ * 136 + mb + r] = f16b(acc[mi][ni][r] + bv);
            }
        }
        __syncthreads();
        const int b = row0 >> 11, m0 = row0 & 2047;
        u16* dst = opT + (size_t)b * NC * NL + (size_t)n0 * NL + m0;
        for (int i = tid; i < 128 * 16; i += 256) {
            const int c = i >> 4, ch = i & 15;
            uint4 v = *(const uint4*)&Ts[c * 136 + ch * 8];
            *(uint4*)&dst[(size_t)c * NL + ch * 8] = v;
        }
    }
}

// ---- FUSED score+softmax --------------------------------------------------
// Grid (32,32), 256 thr / 4 waves. Block = one 64x64 (l,m) tile, ALL 8 b.
// Wave tile 64(m) x 16(n). Per thread: 16 C/D slots x 8 b packed in 64 VGPRs.
// Round 10: BK=128 staged as two stacked 64x64-u16 half-tiles (kh) so the
// ds_read geometry is byte-identical to round 6's zero-conflict layout.
__global__ __launch_bounds__(256) void score_softmax_kernel(
    const u16* __restrict__ xp, const u16* __restrict__ yp, u16* __restrict__ ATT)
{
    __shared__ __align__(16) u16 As[8192], Bs[8192];   // 2 x (64 x 64) u16 each (32 KB)
    const int tid = threadIdx.x;
    const int w = tid >> 6, lane = tid & 63;
    const int row0 = blockIdx.x * 64, col0 = blockIdx.y * 64;
    const int wn = w * 16;
    const int fr = lane & 15, fq = lane >> 4;

    unsigned sv[NB][8];   // [b][mi*2+rp]: lo half r=rp*2, hi half r=rp*2+1

#pragma unroll
    for (int b = 0; b < NB; ++b) {
        const u16* A = xp + (size_t)b * NL * NCI;
        const u16* B = yp + (size_t)b * NL * NCI;
        f32x4 acc[4] = {};
#pragma unroll
        for (int h = 0; h < 2; ++h) {
            const int k0 = h * 128;
            // stage 64x128 A and B as two 64x64 half-tiles (4 passes)
#pragma unroll
            for (int pass = 0; pass < 4; ++pass) {
                const int cbase = pass * 256 + w * 64;   // wave-uniform
                const int chunk = cbase + lane;
                const int kh = chunk >> 9;               // which 64-wide k half
                const int r = (chunk >> 3) & 63;         // m-row 0..63
                const int jj = (chunk & 7) ^ (r & 7);    // XOR-swizzled k-chunk
                gload16(A + (size_t)(row0 + r) * NCI + k0 + kh * 64 + jj * 8, (char*)As + chunk * 16);
                gload16(B + (size_t)(col0 + r) * NCI + k0 + kh * 64 + jj * 8, (char*)Bs + chunk * 16);
            }
            __syncthreads();
#pragma unroll
            for (int kq = 0; kq < 4; ++kq) {
                const int rb = (kq >> 1) * 64;           // half-tile row base
                const int c = (((kq & 1) * 4 + fq) ^ (fr & 7)) * 8;
                f16x8 af[4], bf;
                bf = *(const f16x8*)&Bs[(rb + wn + fr) * 64 + c];
#pragma unroll
                for (int mi = 0; mi < 4; ++mi)
                    af[mi] = *(const f16x8*)&As[(rb + mi * 16 + fr) * 64 + c];
#pragma unroll
                for (int mi = 0; mi < 4; ++mi)
                    acc[mi] = __builtin_amdgcn_mfma_f32_16x16x32_f16(af[mi], bf, acc[mi], 0, 0, 0);
            }
            __syncthreads();
        }
#pragma unroll
        for (int mi = 0; mi < 4; ++mi) {
            sv[b][mi * 2 + 0] = (unsigned)f16b(acc[mi][0]) | ((unsigned)f16b(acc[mi][1]) << 16);
            sv[b][mi * 2 + 1] = (unsigned)f16b(acc[mi][2]) | ((unsigned)f16b(acc[mi][3]) << 16);
        }
    }

    // register-only softmax over b, then write attn fp16
    const int gc = col0 + wn + fr;
#pragma unroll
    for (int mi = 0; mi < 4; ++mi) {
#pragma unroll
        for (int rp = 0; rp < 2; ++rp) {
            float v0[NB], v1[NB];
#pragma unroll
            for (int b = 0; b < NB; ++b) {
                unsigned u = sv[b][mi * 2 + rp];
                v0[b] = f16tof((u16)(u & 0xFFFF));
                v1[b] = f16tof((u16)(u >> 16));
            }
            float m0 = v0[0], m1 = v1[0];
#pragma unroll
            for (int b = 1; b < NB; ++b) { m0 = fmaxf(m0, v0[b]); m1 = fmaxf(m1, v1[b]); }
            float s0 = 0.f, s1 = 0.f;
#pragma unroll
            for (int b = 0; b < NB; ++b) {
                v0[b] = __expf(v0[b] - m0); s0 += v0[b];
                v1[b] = __expf(v1[b] - m1); s1 += v1[b];
            }
            const float i0 = 1.f / s0, i1 = 1.f / s1;
            const int gr0 = row0 + mi * 16 + fq * 4 + rp * 2;
#pragma unroll
            for (int b = 0; b < NB; ++b) {
                u16* dst = ATT + (size_t)b * NL * NL;
                dst[(size_t)gr0 * NL + gc]       = f16b(v0[b] * i0);
                dst[(size_t)(gr0 + 1) * NL + gc] = f16b(v1[b] * i1);
            }
        }
    }
}

// ---- out: out[b] = X[b] + attn[b] @ op[b], 512 thr, issue-early dbuf -------
__global__ __launch_bounds__(512) void out_kernel(
    const u16* __restrict__ ATT, const u16* __restrict__ opT,
    const float* __restrict__ X, float* __restrict__ Out)
{
    __shared__ __align__(16) u16 As[2][8192], Bs[2][8192];   // 128 x 64 each, x2
    const int tid = threadIdx.x;
    const int w = tid >> 6, lane = tid & 63;
    const int b = blockIdx.z;
    const int row0 = blockIdx.x * 128, col0 = blockIdx.y * 128;
    const u16* Aatt = ATT + (size_t)b * NL * NL;
    const u16* Bsrc = opT + (size_t)b * NC * NL;

    f32x4 acc[4][2] = {};
    const int wm = (w & 1) * 64, wn = (w >> 1) * 32;
    const int fr = lane & 15, fq = lane >> 4;

    // staging helper (as lambda): stage K-chunk k0 into buffer bu
    auto stage = [&](int k0, int bu) {
#pragma unroll
        for (int pass = 0; pass < 2; ++pass) {
            const int cbase = pass * 512 + w * 64;   // wave-uniform
            const int chunk = cbase + lane;
            const int r = chunk >> 3;
            const int kc = (chunk & 7) ^ (r & 7);
            gload16(Aatt + (size_t)(row0 + r) * NL + k0 + kc * 8, (char*)&As[bu][0] + cbase * 16);
            gload16(Bsrc + (size_t)(col0 + r) * NL + k0 + kc * 8, (char*)&Bs[bu][0] + cbase * 16);
        }
    };

    stage(0, 0);
    int bu = 0;
    for (int it = 0; it < NL / 64; ++it) {
        __syncthreads();                         // own vmcnt(0) drained -> buf[bu] ready
        if (it + 1 < NL / 64) stage((it + 1) * 64, bu ^ 1);   // issue early, fly during compute
        f16x8 af[4][2], bf[2][2];
#pragma unroll
        for (int mi = 0; mi < 4; ++mi)
#pragma unroll
            for (int kt = 0; kt < 2; ++kt)
                af[mi][kt] = *(const f16x8*)&As[bu][(wm + mi * 16 + fr) * 64 + ((kt * 4 + fq) ^ (fr & 7)) * 8];
#pragma unroll
        for (int ni = 0; ni < 2; ++ni)
#pragma unroll
            for (int kt = 0; kt < 2; ++kt)
                bf[ni][kt] = *(const f16x8*)&Bs[bu][(wn + ni * 16 + fr) * 64 + ((kt * 4 + fq) ^ (fr & 7)) * 8];
#pragma unroll
        for (int kt = 0; kt < 2; ++kt)
#pragma unroll
            for (int mi = 0; mi < 4; ++mi)
#pragma unroll
                for (int ni = 0; ni < 2; ++ni)
                    acc[mi][ni] = __builtin_amdgcn_mfma_f32_16x16x32_f16(af[mi][kt], bf[ni][kt], acc[mi][ni], 0, 0, 0);
        bu ^= 1;
    }
    const size_t ob = (size_t)b * NL * NC;
#pragma unroll
    for (int mi = 0; mi < 4; ++mi) {
        const int gr = row0 + wm + mi * 16 + fq * 4;
#pragma unroll
        for (int ni = 0; ni < 2; ++ni) {
            const int gc = col0 + wn + ni * 16 + fr;
#pragma unroll
            for (int r = 0; r < 4; ++r) {
                const size_t o = ob + (size_t)(gr + r) * NC + gc;
                Out[o] = X[o] + acc[mi][ni][r];
            }
        }
    }
}

extern "C" void kernel_launch(void* const* d_in, const int* in_sizes, int n_in,
                              void* d_out, int out_size, void* d_ws, size_t ws_size,
                              hipStream_t stream)
{
    const float* X  = (const float*)d_in[0];
    const float* Wx = (const float*)d_in[1];
    const float* bx = (const float*)d_in[2];
    const float* Wy = (const float*)d_in[3];
    const float* by = (const float*)d_in[4];
    const float* Wo = (const float*)d_in[5];
    const float* bo = (const float*)d_in[6];
    float* out = (float*)d_out;

    // Workspace (~97 MB): ATT fp16 [0,64MB); Xf16 (16MB) overlaps ATT[0:16MB) —
    // dead (proj done) before score_softmax writes ATT (stream-ordered).
    char* ws = (char*)d_ws;
    u16* ATT = (u16*)ws;
    u16* Xf  = (u16*)ws;
    char* p = ws + 67108864;
    u16* xp  = (u16*)p; p += 8388608;
    u16* yp  = (u16*)p; p += 8388608;
    u16* opT = (u16*)p; p += 16777216;
    u16* WxT = (u16*)p; p += 262144;
    u16* WyT = (u16*)p; p += 262144;
    u16* WoT = (u16*)p; p += 524288;

    cvt_x_kernel<<<4096, 256, 0, stream>>>(X, Xf);
    cvt_w_kernel<<<1024, 256, 0, stream>>>(Wx, Wy, Wo, WxT, WyT, WoT);
    proj_kernel<<<dim3(128, 8), 256, 0, stream>>>(Xf, WxT, WyT, WoT, bx, by, bo, xp, yp, opT);
    score_softmax_kernel<<<dim3(32, 32), 256, 0, stream>>>(xp, yp, ATT);
    out_kernel<<<dim3(16, 4, NB), 512, 0, stream>>>(ATT, opT, X, out);
}

// Round 7
// 201.431 us; speedup vs baseline: 1.1361x; 1.0225x over previous
//
#include <hip/hip_runtime.h>

// NonLocalBlock B=8, L=2048, C=512, CI=256 (fp32 in/out).
// Round 13:
//   - score_softmax: REVERT to round-10 serial structure (known-good 52us,
//     206us total). The counted-vmcnt raw-barrier variant (r11/r12) killed
//     the container twice -> treated as GPU hang; axis abandoned (m152:
//     naive barrier/vmcnt combos race; serial structure is the local best:
//     r7 70us, r8 74us, r10 52us).
//   - out_kernel: + bijective XCD-chunked blockIdx swizzle (T1). 512 blocks,
//     512%8==0. Each XCD now owns exactly one batch: opT[b] (2MB) becomes
//     L2-resident, ATT[b] row-panels get L2 reuse across the 4 col-tile
//     blocks (all 64 chunk-blocks co-resident at 2 blocks/CU).
//   All-fp16, XOR k-chunk swizzle (0 bank conflicts).

#define NB 8
#define NL 2048
#define NC 512
#define NCI 256

using f16x8 = __attribute__((ext_vector_type(8))) _Float16;
using f32x4 = __attribute__((ext_vector_type(4))) float;
typedef unsigned short u16;

__device__ __forceinline__ u16 f16b(float x) {
    _Float16 h = (_Float16)x;
    return __builtin_bit_cast(u16, h);
}
__device__ __forceinline__ float f16tof(u16 u) {
    return (float)__builtin_bit_cast(_Float16, u);
}
__device__ __forceinline__ void gload16(const void* g, void* l) {
    __builtin_amdgcn_global_load_lds((__attribute__((address_space(1))) void*)g,
                                     (__attribute__((address_space(3))) void*)l,
                                     16, 0, 0);
}

// ---- cvt: X fp32 -> fp16 --------------------------------------------------
__global__ __launch_bounds__(256) void cvt_x_kernel(const float* __restrict__ X,
                                                    u16* __restrict__ Xf)
{
    size_t i = (size_t)blockIdx.x * 256 + threadIdx.x;   // per 8 elements
    const float4* X4 = (const float4*)X;
    float4 a = X4[2 * i], b = X4[2 * i + 1];
    u16 o[8] = {f16b(a.x), f16b(a.y), f16b(a.z), f16b(a.w),
                f16b(b.x), f16b(b.y), f16b(b.z), f16b(b.w)};
    ((uint4*)Xf)[i] = *(const uint4*)o;
}

// ---- cvt: transpose weights to [n][k] fp16 --------------------------------
__global__ __launch_bounds__(256) void cvt_w_kernel(
    const float* __restrict__ Wx, const float* __restrict__ Wy, const float* __restrict__ Wo,
    u16* __restrict__ WxT, u16* __restrict__ WyT, u16* __restrict__ WoT)
{
    const int bid = blockIdx.x, t = threadIdx.x;
#pragma unroll
    for (int kk = 0; kk < 2; ++kk) {
        const int k = t + kk * 256;
        if (bid < 256)      WxT[(size_t)bid * NC + k] = f16b(Wx[(size_t)k * NCI + bid]);
        else if (bid < 512) WyT[(size_t)(bid - 256) * NC + k] = f16b(Wy[(size_t)k * NCI + (bid - 256)]);
        else                WoT[(size_t)(bid - 512) * NC + k] = f16b(Wo[(size_t)k * NC + (bid - 512)]);
    }
}

// ---- projections: grid (128, 8); cb 0-1 xp, 2-3 yp, 4-7 op (transposed) ----
__global__ __launch_bounds__(256) void proj_kernel(
    const u16* __restrict__ Xf,
    const u16* __restrict__ WxT, const u16* __restrict__ WyT, const u16* __restrict__ WoT,
    const float* __restrict__ bx, const float* __restrict__ by, const float* __restrict__ bo,
    u16* __restrict__ xp, u16* __restrict__ yp, u16* __restrict__ opT)
{
    __shared__ __align__(16) u16 SM[17408];   // As 8192 + Bs 8192; Ts reuse 128x136
    u16* As = SM;
    u16* Bs = SM + 8192;

    const int tid = threadIdx.x;
    const int w = tid >> 6, lane = tid & 63;
    const int row0 = blockIdx.x * 128;
    const int cb = blockIdx.y;

    const u16* W; const float* bias; int n0, path;
    if (cb < 2)      { path = 0; n0 = cb * 128;       W = WxT; bias = bx; }
    else if (cb < 4) { path = 1; n0 = (cb - 2) * 128; W = WyT; bias = by; }
    else             { path = 2; n0 = (cb - 4) * 128; W = WoT; bias = bo; }

    f32x4 acc[4][4] = {};
    const int wm = (w & 1) * 64, wn = (w >> 1) * 64;
    const int fr = lane & 15, fq = lane >> 4;

    for (int k0 = 0; k0 < NC; k0 += 64) {
#pragma unroll
        for (int pass = 0; pass < 4; ++pass) {
            const int cbase = pass * 256 + w * 64;   // wave-uniform
            const int chunk = cbase + lane;
            const int r = chunk >> 3;
            const int kc = (chunk & 7) ^ (r & 7);    // XOR-swizzled k-chunk
            gload16(Xf + (size_t)(row0 + r) * NC + k0 + kc * 8, (char*)As + cbase * 16);
            gload16(W  + (size_t)(n0  + r) * NC + k0 + kc * 8, (char*)Bs + cbase * 16);
        }
        __syncthreads();
        f16x8 a[4][2], b[4][2];
#pragma unroll
        for (int mi = 0; mi < 4; ++mi)
#pragma unroll
            for (int kt = 0; kt < 2; ++kt)
                a[mi][kt] = *(const f16x8*)&As[(wm + mi * 16 + fr) * 64 + ((kt * 4 + fq) ^ (fr & 7)) * 8];
#pragma unroll
        for (int ni = 0; ni < 4; ++ni)
#pragma unroll
            for (int kt = 0; kt < 2; ++kt)
                b[ni][kt] = *(const f16x8*)&Bs[(wn + ni * 16 + fr) * 64 + ((kt * 4 + fq) ^ (fr & 7)) * 8];
#pragma unroll
        for (int kt = 0; kt < 2; ++kt)
#pragma unroll
            for (int mi = 0; mi < 4; ++mi)
#pragma unroll
                for (int ni = 0; ni < 4; ++ni)
                    acc[mi][ni] = __builtin_amdgcn_mfma_f32_16x16x32_f16(a[mi][kt], b[ni][kt], acc[mi][ni], 0, 0, 0);
        __syncthreads();
    }

    if (path != 2) {
        u16* O = (path == 0) ? xp : yp;
#pragma unroll
        for (int mi = 0; mi < 4; ++mi) {
            const int grow = row0 + wm + mi * 16 + fq * 4;
#pragma unroll
            for (int ni = 0; ni < 4; ++ni) {
                const int gcol = n0 + wn + ni * 16 + fr;
                const float bv = bias[gcol];
#pragma unroll
                for (int r = 0; r < 4; ++r)
                    O[(size_t)(grow + r) * NCI + gcol] = f16b(acc[mi][ni][r] + bv);
            }
        }
    } else {
        u16* Ts = SM;   // 128 x 136 fp16 transpose staging
#pragma unroll
        for (int mi = 0; mi < 4; ++mi) {
            const int mb = wm + mi * 16 + fq * 4;
#pragma unroll
            for (int ni = 0; ni < 4; ++ni) {
                const int nl_ = wn + ni * 16 + fr;
                const float bv = bias[n0 + nl_];
#pragma unroll
                for (int r = 0; r < 4; ++r)
                    Ts[nl_ * 136 + mb + r] = f16b(acc[mi][ni][r] + bv);
            }
        }
        __syncthreads();
        const int b = row0 >> 11, m0 = row0 & 2047;
        u16* dst = opT + (size_t)b * NC * NL + (size_t)n0 * NL + m0;
        for (int i = tid; i < 128 * 16; i += 256) {
            const int c = i >> 4, ch = i & 15;
            uint4 v = *(const uint4*)&Ts[c * 136 + ch * 8];
            *(uint4*)&dst[(size_t)c * NL + ch * 8] = v;
        }
    }
}

// ---- FUSED score+softmax --------------------------------------------------
// Grid (32,32), 256 thr / 4 waves. Block = one 64x64 (l,m) tile, ALL 8 b.
// Wave tile 64(m) x 16(n). Per thread: 16 C/D slots x 8 b packed in 64 VGPRs.
// Round 13 = round 10: BK=128 staged as two stacked 64x64-u16 half-tiles (kh)
// so the ds_read geometry is byte-identical to round 6's zero-conflict layout.
__global__ __launch_bounds__(256) void score_softmax_kernel(
    const u16* __restrict__ xp, const u16* __restrict__ yp, u16* __restrict__ ATT)
{
    __shared__ __align__(16) u16 As[8192], Bs[8192];   // 2 x (64 x 64) u16 each (32 KB)
    const int tid = threadIdx.x;
    const int w = tid >> 6, lane = tid & 63;
    const int row0 = blockIdx.x * 64, col0 = blockIdx.y * 64;
    const int wn = w * 16;
    const int fr = lane & 15, fq = lane >> 4;

    unsigned sv[NB][8];   // [b][mi*2+rp]: lo half r=rp*2, hi half r=rp*2+1

#pragma unroll
    for (int b = 0; b < NB; ++b) {
        const u16* A = xp + (size_t)b * NL * NCI;
        const u16* B = yp + (size_t)b * NL * NCI;
        f32x4 acc[4] = {};
#pragma unroll
        for (int h = 0; h < 2; ++h) {
            const int k0 = h * 128;
            // stage 64x128 A and B as two 64x64 half-tiles (4 passes)
#pragma unroll
            for (int pass = 0; pass < 4; ++pass) {
                const int cbase = pass * 256 + w * 64;   // wave-uniform
                const int chunk = cbase + lane;
                const int kh = chunk >> 9;               // which 64-wide k half
                const int r = (chunk >> 3) & 63;         // m-row 0..63
                const int jj = (chunk & 7) ^ (r & 7);    // XOR-swizzled k-chunk
                gload16(A + (size_t)(row0 + r) * NCI + k0 + kh * 64 + jj * 8, (char*)As + chunk * 16);
                gload16(B + (size_t)(col0 + r) * NCI + k0 + kh * 64 + jj * 8, (char*)Bs + chunk * 16);
            }
            __syncthreads();
#pragma unroll
            for (int kq = 0; kq < 4; ++kq) {
                const int rb = (kq >> 1) * 64;           // half-tile row base
                const int c = (((kq & 1) * 4 + fq) ^ (fr & 7)) * 8;
                f16x8 af[4], bf;
                bf = *(const f16x8*)&Bs[(rb + wn + fr) * 64 + c];
#pragma unroll
                for (int mi = 0; mi < 4; ++mi)
                    af[mi] = *(const f16x8*)&As[(rb + mi * 16 + fr) * 64 + c];
#pragma unroll
                for (int mi = 0; mi < 4; ++mi)
                    acc[mi] = __builtin_amdgcn_mfma_f32_16x16x32_f16(af[mi], bf, acc[mi], 0, 0, 0);
            }
            __syncthreads();
        }
#pragma unroll
        for (int mi = 0; mi < 4; ++mi) {
            sv[b][mi * 2 + 0] = (unsigned)f16b(acc[mi][0]) | ((unsigned)f16b(acc[mi][1]) << 16);
            sv[b][mi * 2 + 1] = (unsigned)f16b(acc[mi][2]) | ((unsigned)f16b(acc[mi][3]) << 16);
        }
    }

    // register-only softmax over b, then write attn fp16
    const int gc = col0 + wn + fr;
#pragma unroll
    for (int mi = 0; mi < 4; ++mi) {
#pragma unroll
        for (int rp = 0; rp < 2; ++rp) {
            float v0[NB], v1[NB];
#pragma unroll
            for (int b = 0; b < NB; ++b) {
                unsigned u = sv[b][mi * 2 + rp];
                v0[b] = f16tof((u16)(u & 0xFFFF));
                v1[b] = f16tof((u16)(u >> 16));
            }
            float m0 = v0[0], m1 = v1[0];
#pragma unroll
            for (int b = 1; b < NB; ++b) { m0 = fmaxf(m0, v0[b]); m1 = fmaxf(m1, v1[b]); }
            float s0 = 0.f, s1 = 0.f;
#pragma unroll
            for (int b = 0; b < NB; ++b) {
                v0[b] = __expf(v0[b] - m0); s0 += v0[b];
                v1[b] = __expf(v1[b] - m1); s1 += v1[b];
            }
            const float i0 = 1.f / s0, i1 = 1.f / s1;
            const int gr0 = row0 + mi * 16 + fq * 4 + rp * 2;
#pragma unroll
            for (int b = 0; b < NB; ++b) {
                u16* dst = ATT + (size_t)b * NL * NL;
                dst[(size_t)gr0 * NL + gc]       = f16b(v0[b] * i0);
                dst[(size_t)(gr0 + 1) * NL + gc] = f16b(v1[b] * i1);
            }
        }
    }
}

// ---- out: out[b] = X[b] + attn[b] @ op[b], 512 thr, issue-early dbuf -------
// Round 13: bijective XCD-chunked swizzle (512 blocks, 512%8==0) — each XCD
// owns one batch: opT[b] (2MB) L2-resident, ATT[b] panels L2-reused.
__global__ __launch_bounds__(512) void out_kernel(
    const u16* __restrict__ ATT, const u16* __restrict__ opT,
    const float* __restrict__ X, float* __restrict__ Out)
{
    __shared__ __align__(16) u16 As[2][8192], Bs[2][8192];   // 128 x 64 each, x2
    const int tid = threadIdx.x;
    const int w = tid >> 6, lane = tid & 63;

    // linear dispatch id (x-fastest) -> XCD-chunked remap (bijective: 512%8==0)
    const int id  = blockIdx.x + 16 * (blockIdx.y + 4 * blockIdx.z);
    const int nid = (id & 7) * 64 + (id >> 3);   // chunk = 512/8 = 64
    const int bx  = nid & 15;                    // row tile 0..15
    const int by  = (nid >> 4) & 3;              // col tile 0..3
    const int b   = nid >> 6;                    // batch 0..7

    const int row0 = bx * 128, col0 = by * 128;
    const u16* Aatt = ATT + (size_t)b * NL * NL;
    const u16* Bsrc = opT + (size_t)b * NC * NL;

    f32x4 acc[4][2] = {};
    const int wm = (w & 1) * 64, wn = (w >> 1) * 32;
    const int fr = lane & 15, fq = lane >> 4;

    // staging helper (as lambda): stage K-chunk k0 into buffer bu
    auto stage = [&](int k0, int bu) {
#pragma unroll
        for (int pass = 0; pass < 2; ++pass) {
            const int cbase = pass * 512 + w * 64;   // wave-uniform
            const int chunk = cbase + lane;
            const int r = chunk >> 3;
            const int kc = (chunk & 7) ^ (r & 7);
            gload16(Aatt + (size_t)(row0 + r) * NL + k0 + kc * 8, (char*)&As[bu][0] + cbase * 16);
            gload16(Bsrc + (size_t)(col0 + r) * NL + k0 + kc * 8, (char*)&Bs[bu][0] + cbase * 16);
        }
    };

    stage(0, 0);
    int bu = 0;
    for (int it = 0; it < NL / 64; ++it) {
        __syncthreads();                         // own vmcnt(0) drained -> buf[bu] ready
        if (it + 1 < NL / 64) stage((it + 1) * 64, bu ^ 1);   // issue early, fly during compute
        f16x8 af[4][2], bf[2][2];
#pragma unroll
        for (int mi = 0; mi < 4; ++mi)
#pragma unroll
            for (int kt = 0; kt < 2; ++kt)
                af[mi][kt] = *(const f16x8*)&As[bu][(wm + mi * 16 + fr) * 64 + ((kt * 4 + fq) ^ (fr & 7)) * 8];
#pragma unroll
        for (int ni = 0; ni < 2; ++ni)
#pragma unroll
            for (int kt = 0; kt < 2; ++kt)
                bf[ni][kt] = *(const f16x8*)&Bs[bu][(wn + ni * 16 + fr) * 64 + ((kt * 4 + fq) ^ (fr & 7)) * 8];
#pragma unroll
        for (int kt = 0; kt < 2; ++kt)
#pragma unroll
            for (int mi = 0; mi < 4; ++mi)
#pragma unroll
                for (int ni = 0; ni < 2; ++ni)
                    acc[mi][ni] = __builtin_amdgcn_mfma_f32_16x16x32_f16(af[mi][kt], bf[ni][kt], acc[mi][ni], 0, 0, 0);
        bu ^= 1;
    }
    const size_t ob = (size_t)b * NL * NC;
#pragma unroll
    for (int mi = 0; mi < 4; ++mi) {
        const int gr = row0 + wm + mi * 16 + fq * 4;
#pragma unroll
        for (int ni = 0; ni < 2; ++ni) {
            const int gc = col0 + wn + ni * 16 + fr;
#pragma unroll
            for (int r = 0; r < 4; ++r) {
                const size_t o = ob + (size_t)(gr + r) * NC + gc;
                Out[o] = X[o] + acc[mi][ni][r];
            }
        }
    }
}

extern "C" void kernel_launch(void* const* d_in, const int* in_sizes, int n_in,
                              void* d_out, int out_size, void* d_ws, size_t ws_size,
                              hipStream_t stream)
{
    const float* X  = (const float*)d_in[0];
    const float* Wx = (const float*)d_in[1];
    const float* bx = (const float*)d_in[2];
    const float* Wy = (const float*)d_in[3];
    const float* by = (const float*)d_in[4];
    const float* Wo = (const float*)d_in[5];
    const float* bo = (const float*)d_in[6];
    float* out = (float*)d_out;

    // Workspace (~97 MB): ATT fp16 [0,64MB); Xf16 (16MB) overlaps ATT[0:16MB) —
    // dead (proj done) before score_softmax writes ATT (stream-ordered).
    char* ws = (char*)d_ws;
    u16* ATT = (u16*)ws;
    u16* Xf  = (u16*)ws;
    char* p = ws + 67108864;
    u16* xp  = (u16*)p; p += 8388608;
    u16* yp  = (u16*)p; p += 8388608;
    u16* opT = (u16*)p; p += 16777216;
    u16* WxT = (u16*)p; p += 262144;
    u16* WyT = (u16*)p; p += 262144;
    u16* WoT = (u16*)p; p += 524288;

    cvt_x_kernel<<<4096, 256, 0, stream>>>(X, Xf);
    cvt_w_kernel<<<1024, 256, 0, stream>>>(Wx, Wy, Wo, WxT, WyT, WoT);
    proj_kernel<<<dim3(128, 8), 256, 0, stream>>>(Xf, WxT, WyT, WoT, bx, by, bo, xp, yp, opT);
    score_softmax_kernel<<<dim3(32, 32), 256, 0, stream>>>(xp, yp, ATT);
    out_kernel<<<dim3(16, 4, NB), 512, 0, stream>>>(ATT, opT, X, out);
}